// Round 11
// baseline (2215.793 us; speedup 1.0000x reference)
//
#include <hip/hip_runtime.h>

// ---------------------------------------------------------------------------
// MutualRec forward: 5x GATv2 + ChebConv(k=3) + mutualistic MLP + edge dots
// R11: GEMM family rebuilt as "X-tile in LDS": 64-row tiles staged
//      cooperatively with coalesced float4 loads (vmcnt path, one wait per
//      tile), compute reads X via uniform-address LDS b128 broadcast and W
//      via lane-indexed b32 (both conflict-free). No scalar-load X chain.
//      Graph kernels (CSR GAT/cheb), dots, sorts unchanged from R10.
// ---------------------------------------------------------------------------

#define LRELU_SLOPE 0.2f
#define EDGE_BLOCKS 2048

__device__ __forceinline__ float f4get(const float4& v, int k) {
  return (k == 0) ? v.x : (k == 1) ? v.y : (k == 2) ? v.z : v.w;
}

// Stage one 64x64 f32 tile (tile t of X, N rows total) into Xs[4096].
__device__ __forceinline__ void stage_tile(const float* __restrict__ X, int t, int N,
                                           float* __restrict__ Xs) {
  const size_t base = (size_t)t * 4096;
#pragma unroll
  for (int j = 0; j < 4; ++j) {
    const int i = threadIdx.x + j * 256;          // float4 index within tile
    const size_t gi = base + (size_t)i * 4;       // global float index
    const int r = (int)(gi >> 6);                 // global row
    float4 v = make_float4(0.f, 0.f, 0.f, 0.f);
    if (r < N) v = *(const float4*)(X + gi);
    *(float4*)(Xs + i * 4) = v;
  }
}

// ============================ GEMM family ==================================
// Y[N,64] = sum_m X_m[N,64] @ W[m] + b ; W is [NMAT*64,64] row-major stacked.
template <int NMAT>
__global__ void gemm_lds_k(const float* __restrict__ X0,
                           const float* __restrict__ X1,
                           const float* __restrict__ X2,
                           const float* __restrict__ W,
                           const float* __restrict__ b,
                           float* __restrict__ Y, int N) {
  __shared__ float Ws[NMAT * 4096];
  __shared__ float Xs[4096];
  for (int i = threadIdx.x; i < NMAT * 4096; i += 256) Ws[i] = W[i];
  const int lane = threadIdx.x & 63;
  const int wv = threadIdx.x >> 6;
  const int ntile = (N + 63) >> 6;
  const float bj = b[lane];
  for (int t = blockIdx.x; t < ntile; t += gridDim.x) {
    float y[16];
#pragma unroll
    for (int j = 0; j < 16; ++j) y[j] = bj;
#pragma unroll
    for (int m = 0; m < NMAT; ++m) {
      const float* Xm = (m == 0) ? X0 : ((m == 1) ? X1 : X2);
      __syncthreads();                 // protect Xs (and W on first pass)
      stage_tile(Xm, t, N, Xs);
      __syncthreads();
      const float* wm = Ws + m * 4096;
#pragma unroll
      for (int q = 0; q < 4; ++q) {
        const int r0l = (wv * 16 + q * 4) * 64;   // local row offset in Xs
        float a0 = y[q * 4 + 0], a1 = y[q * 4 + 1];
        float a2 = y[q * 4 + 2], a3 = y[q * 4 + 3];
#pragma unroll 4
        for (int kc = 0; kc < 64; kc += 4) {
          const float4 xa = *(const float4*)(Xs + r0l + kc);
          const float4 xb = *(const float4*)(Xs + r0l + 64 + kc);
          const float4 xc = *(const float4*)(Xs + r0l + 128 + kc);
          const float4 xd = *(const float4*)(Xs + r0l + 192 + kc);
#pragma unroll
          for (int kk = 0; kk < 4; ++kk) {
            const float w = wm[(kc + kk) * 64 + lane];
            a0 = fmaf(f4get(xa, kk), w, a0);
            a1 = fmaf(f4get(xb, kk), w, a1);
            a2 = fmaf(f4get(xc, kk), w, a2);
            a3 = fmaf(f4get(xd, kk), w, a3);
          }
        }
        y[q * 4 + 0] = a0; y[q * 4 + 1] = a1;
        y[q * 4 + 2] = a2; y[q * 4 + 3] = a3;
      }
    }
#pragma unroll
    for (int j = 0; j < 16; ++j) {
      const int r = t * 64 + wv * 16 + j;
      if (r < N) Y[(size_t)r * 64 + lane] = y[j];
    }
  }
}

// ---- proj_k<NP>: Y_p = X @ W_p + b_p. Stage X once, NP projections. ----
template <int NP>
__global__ void proj_k(const float* __restrict__ X,
                       const float* __restrict__ W0, const float* __restrict__ W1,
                       const float* __restrict__ b0, const float* __restrict__ b1,
                       float* __restrict__ Y0, float* __restrict__ Y1, int N) {
  __shared__ float Ws[NP * 4096];
  __shared__ float Xs[4096];
  for (int i = threadIdx.x; i < 4096; i += 256) Ws[i] = W0[i];
  if (NP > 1) for (int i = threadIdx.x; i < 4096; i += 256) Ws[4096 + i] = W1[i];
  const int lane = threadIdx.x & 63;
  const int wv = threadIdx.x >> 6;
  const int ntile = (N + 63) >> 6;
  const float bj0 = b0[lane];
  const float bj1 = (NP > 1) ? b1[lane] : 0.0f;
  for (int t = blockIdx.x; t < ntile; t += gridDim.x) {
    __syncthreads();
    stage_tile(X, t, N, Xs);
    __syncthreads();
    float y0[16], y1[16];
#pragma unroll
    for (int j = 0; j < 16; ++j) { y0[j] = bj0; y1[j] = bj1; }
#pragma unroll
    for (int q = 0; q < 4; ++q) {
      const int r0l = (wv * 16 + q * 4) * 64;
      float a0 = y0[q*4+0], a1 = y0[q*4+1], a2 = y0[q*4+2], a3 = y0[q*4+3];
      float c0 = y1[q*4+0], c1 = y1[q*4+1], c2 = y1[q*4+2], c3 = y1[q*4+3];
#pragma unroll 4
      for (int kc = 0; kc < 64; kc += 4) {
        const float4 xa = *(const float4*)(Xs + r0l + kc);
        const float4 xb = *(const float4*)(Xs + r0l + 64 + kc);
        const float4 xc = *(const float4*)(Xs + r0l + 128 + kc);
        const float4 xd = *(const float4*)(Xs + r0l + 192 + kc);
#pragma unroll
        for (int kk = 0; kk < 4; ++kk) {
          const float wA = Ws[(kc + kk) * 64 + lane];
          a0 = fmaf(f4get(xa, kk), wA, a0);
          a1 = fmaf(f4get(xb, kk), wA, a1);
          a2 = fmaf(f4get(xc, kk), wA, a2);
          a3 = fmaf(f4get(xd, kk), wA, a3);
          if (NP > 1) {
            const float wB = Ws[4096 + (kc + kk) * 64 + lane];
            c0 = fmaf(f4get(xa, kk), wB, c0);
            c1 = fmaf(f4get(xb, kk), wB, c1);
            c2 = fmaf(f4get(xc, kk), wB, c2);
            c3 = fmaf(f4get(xd, kk), wB, c3);
          }
        }
      }
      y0[q*4+0] = a0; y0[q*4+1] = a1; y0[q*4+2] = a2; y0[q*4+3] = a3;
      y1[q*4+0] = c0; y1[q*4+1] = c1; y1[q*4+2] = c2; y1[q*4+3] = c3;
    }
#pragma unroll
    for (int j = 0; j < 16; ++j) {
      const int r = t * 64 + wv * 16 + j;
      if (r < N) {
        Y0[(size_t)r * 64 + lane] = y0[j];
        if (NP > 1) Y1[(size_t)r * 64 + lane] = y1[j];
      }
    }
  }
}

// ---- dual128_k<SHARED>: Y0=[A0,C0]@W0+b0 ; Y1=[A1,C1]@W1+b1 (W: [128,64]).
// SHARED: C0==C1 (staged once, feeds both).
template <bool SHARED>
__global__ void dual128_k(const float* __restrict__ A0, const float* __restrict__ C0,
                          const float* __restrict__ A1, const float* __restrict__ C1,
                          const float* __restrict__ W0, const float* __restrict__ W1,
                          const float* __restrict__ b0, const float* __restrict__ b1,
                          float* __restrict__ Y0, float* __restrict__ Y1, int N) {
  __shared__ float Ws[2 * 8192];
  __shared__ float Xs[4096];
  for (int i = threadIdx.x; i < 8192; i += 256) Ws[i] = W0[i];
  for (int i = threadIdx.x; i < 8192; i += 256) Ws[8192 + i] = W1[i];
  const int lane = threadIdx.x & 63;
  const int wv = threadIdx.x >> 6;
  const int ntile = (N + 63) >> 6;
  const float bj0 = b0[lane], bj1 = b1[lane];
  for (int t = blockIdx.x; t < ntile; t += gridDim.x) {
    float y0[16], y1[16];
#pragma unroll
    for (int j = 0; j < 16; ++j) { y0[j] = bj0; y1[j] = bj1; }
    const int NIN = SHARED ? 3 : 4;
    for (int m = 0; m < NIN; ++m) {
      const float* Xm;
      if (SHARED) Xm = (m == 0) ? A0 : ((m == 1) ? A1 : C0);
      else        Xm = (m == 0) ? A0 : ((m == 1) ? A1 : ((m == 2) ? C0 : C1));
      __syncthreads();
      stage_tile(Xm, t, N, Xs);
      __syncthreads();
      // which accumulator(s) + W offset this input feeds:
      // m==0: ya with W0 rows 0..63 ; m==1: yb with W1 rows 0..63
      // SHARED m==2: both, W rows 64..127 ; else m==2: ya, m==3: yb.
      const bool doA = (m == 0) || (SHARED && m == 2) || (!SHARED && m == 2);
      const bool doB = (m == 1) || (SHARED && m == 2) || (!SHARED && m == 3);
      const int wrow = (m < 2) ? 0 : 64;
#pragma unroll
      for (int q = 0; q < 4; ++q) {
        const int r0l = (wv * 16 + q * 4) * 64;
        float a0 = y0[q*4+0], a1 = y0[q*4+1], a2 = y0[q*4+2], a3 = y0[q*4+3];
        float c0 = y1[q*4+0], c1 = y1[q*4+1], c2 = y1[q*4+2], c3 = y1[q*4+3];
#pragma unroll 4
        for (int kc = 0; kc < 64; kc += 4) {
          const float4 xa = *(const float4*)(Xs + r0l + kc);
          const float4 xb = *(const float4*)(Xs + r0l + 64 + kc);
          const float4 xc = *(const float4*)(Xs + r0l + 128 + kc);
          const float4 xd = *(const float4*)(Xs + r0l + 192 + kc);
#pragma unroll
          for (int kk = 0; kk < 4; ++kk) {
            if (doA) {
              const float wA = Ws[(wrow + kc + kk) * 64 + lane];
              a0 = fmaf(f4get(xa, kk), wA, a0);
              a1 = fmaf(f4get(xb, kk), wA, a1);
              a2 = fmaf(f4get(xc, kk), wA, a2);
              a3 = fmaf(f4get(xd, kk), wA, a3);
            }
            if (doB) {
              const float wB = Ws[8192 + (wrow + kc + kk) * 64 + lane];
              c0 = fmaf(f4get(xa, kk), wB, c0);
              c1 = fmaf(f4get(xb, kk), wB, c1);
              c2 = fmaf(f4get(xc, kk), wB, c2);
              c3 = fmaf(f4get(xd, kk), wB, c3);
            }
          }
        }
        y0[q*4+0] = a0; y0[q*4+1] = a1; y0[q*4+2] = a2; y0[q*4+3] = a3;
        y1[q*4+0] = c0; y1[q*4+1] = c1; y1[q*4+2] = c2; y1[q*4+3] = c3;
      }
    }
#pragma unroll
    for (int j = 0; j < 16; ++j) {
      const int r = t * 64 + wv * 16 + j;
      if (r < N) {
        Y0[(size_t)r * 64 + lane] = y0[j];
        Y1[(size_t)r * 64 + lane] = y1[j];
      }
    }
  }
}

// ========================= CSR build (counting sort) =======================
__global__ void hist_k(const int* __restrict__ key, int* __restrict__ cnt, int E) {
  const int e = blockIdx.x * blockDim.x + threadIdx.x;
  if (e < E) atomicAdd(cnt + key[e], 1);
}

__global__ void scan1_k(const int* __restrict__ in, int* __restrict__ out,
                        int* __restrict__ bsum, int n) {
  __shared__ int tmp[256];
  const int t = threadIdx.x;
  const int base = blockIdx.x * 1024 + t * 4;
  int v0 = (base + 0 < n) ? in[base + 0] : 0;
  int v1 = (base + 1 < n) ? in[base + 1] : 0;
  int v2 = (base + 2 < n) ? in[base + 2] : 0;
  int v3 = (base + 3 < n) ? in[base + 3] : 0;
  const int s = v0 + v1 + v2 + v3;
  tmp[t] = s;
  __syncthreads();
  for (int off = 1; off < 256; off <<= 1) {
    const int x = (t >= off) ? tmp[t - off] : 0;
    __syncthreads();
    tmp[t] += x;
    __syncthreads();
  }
  const int excl = tmp[t] - s;
  if (t == 255) bsum[blockIdx.x] = tmp[255];
  if (base + 0 < n) out[base + 0] = excl;
  if (base + 1 < n) out[base + 1] = excl + v0;
  if (base + 2 < n) out[base + 2] = excl + v0 + v1;
  if (base + 3 < n) out[base + 3] = excl + v0 + v1 + v2;
}
__global__ void scan2_k(int* __restrict__ bsum, int nb) {
  if (threadIdx.x == 0) {
    int acc = 0;
    for (int i = 0; i < nb; ++i) { const int v = bsum[i]; bsum[i] = acc; acc += v; }
  }
}
__global__ void scan3_k(int* __restrict__ out, const int* __restrict__ bsum, int n) {
  const int i = blockIdx.x * blockDim.x + threadIdx.x;
  if (i < n) out[i] += bsum[i >> 10];
}

__global__ void scatter_k(const int* __restrict__ key, const int* __restrict__ other,
                          int* __restrict__ cursor, int* __restrict__ srt, int E) {
  const int e = blockIdx.x * blockDim.x + threadIdx.x;
  if (e < E) {
    const int p = atomicAdd(cursor + key[e], 1);
    srt[p] = other[e];
  }
}

// ======================= CSR-based graph kernels ===========================
__global__ void gat_csr_k(const float* __restrict__ fs, const float* __restrict__ fd,
                          const float* __restrict__ attn,
                          const int* __restrict__ rowptr, const int* __restrict__ nbr,
                          float* __restrict__ out, int N) {
  const int lane = threadIdx.x & 63;
  const int wid = (blockIdx.x * blockDim.x + threadIdx.x) >> 6;
  const int nw = (gridDim.x * blockDim.x) >> 6;
  const float aw = attn[lane];
  for (int n = wid; n < N; n += nw) {
    const int beg = rowptr[n], end = rowptr[n + 1];
    const float fdv = fd[(size_t)n * 64 + lane];
    float acc = 0.0f, den = 0.0f;
    int e = beg;
    for (; e + 1 < end; e += 2) {
      const int s0 = nbr[e], s1 = nbr[e + 1];
      const float f0 = fs[(size_t)s0 * 64 + lane];
      const float f1 = fs[(size_t)s1 * 64 + lane];
      float v0 = f0 + fdv; v0 = v0 > 0.0f ? v0 : LRELU_SLOPE * v0;
      float v1 = f1 + fdv; v1 = v1 > 0.0f ? v1 : LRELU_SLOPE * v1;
      float p0 = v0 * aw, p1 = v1 * aw;
#pragma unroll
      for (int o = 32; o; o >>= 1) {
        p0 += __shfl_xor(p0, o, 64);
        p1 += __shfl_xor(p1, o, 64);
      }
      const float e0 = __expf(p0), e1 = __expf(p1);
      den += e0 + e1;
      acc = fmaf(e0, f0, acc);
      acc = fmaf(e1, f1, acc);
    }
    if (e < end) {
      const int s0 = nbr[e];
      const float f0 = fs[(size_t)s0 * 64 + lane];
      float v0 = f0 + fdv; v0 = v0 > 0.0f ? v0 : LRELU_SLOPE * v0;
      float p0 = v0 * aw;
#pragma unroll
      for (int o = 32; o; o >>= 1) p0 += __shfl_xor(p0, o, 64);
      const float e0 = __expf(p0);
      den += e0;
      acc = fmaf(e0, f0, acc);
    }
    const float inv = den > 0.0f ? 1.0f / den : 0.0f;
    out[(size_t)n * 64 + lane] = acc * inv;
  }
}

// Fused Cheb step (MODE 1: T1; MODE 2: T2)
template <int MODE>
__global__ void cheb_csr_k(const float* __restrict__ x, const float* __restrict__ T0,
                           const float* __restrict__ Tp, const float* __restrict__ dinv,
                           const float* __restrict__ lam,
                           const int* __restrict__ rowptr, const int* __restrict__ nbr,
                           float* __restrict__ outT, int N) {
  const float re = 2.0f / lam[0];
  const int lane = threadIdx.x & 63;
  const int wid = (blockIdx.x * blockDim.x + threadIdx.x) >> 6;
  const int nw = (gridDim.x * blockDim.x) >> 6;
  for (int n = wid; n < N; n += nw) {
    const int beg = rowptr[n], end = rowptr[n + 1];
    float acc = 0.0f;
    int e = beg;
    for (; e + 1 < end; e += 2) {
      const int s0 = nbr[e], s1 = nbr[e + 1];
      acc = fmaf(x[(size_t)s0 * 64 + lane], dinv[s0], acc);
      acc = fmaf(x[(size_t)s1 * 64 + lane], dinv[s1], acc);
    }
    if (e < end) {
      const int s0 = nbr[e];
      acc = fmaf(x[(size_t)s0 * 64 + lane], dinv[s0], acc);
    }
    const float hv = acc * dinv[n];
    float r;
    if (MODE == 1) {
      r = -re * hv + (re - 1.0f) * T0[(size_t)n * 64 + lane];
    } else {
      r = -2.0f * re * hv + 2.0f * (re - 1.0f) * Tp[(size_t)n * 64 + lane]
          - T0[(size_t)n * 64 + lane];
    }
    outT[(size_t)n * 64 + lane] = r;
  }
}

__global__ void dinv_k(const int* __restrict__ rowptr, float* __restrict__ dinv, int N) {
  const int i = blockIdx.x * blockDim.x + threadIdx.x;
  if (i < N) {
    const float deg = (float)(rowptr[i + 1] - rowptr[i]);
    dinv[i] = rsqrtf(fmaxf(deg, 1.0f));
  }
}

// ---- mutualistic ----
__global__ void mut_k(const float* __restrict__ hP, const float* __restrict__ hS,
                      float* __restrict__ mP, float* __restrict__ mS, int N) {
  const int lane = threadIdx.x & 63;
  const int u = (blockIdx.x * blockDim.x + threadIdx.x) >> 6;
  if (u >= N) return;
  const float p = hP[(size_t)u * 64 + lane];
  const float s = hS[(size_t)u * 64 + lane];
  const float m = p * s;
  float mxp = p, mxs = s;
#pragma unroll
  for (int o = 32; o; o >>= 1) {
    mxp = fmaxf(mxp, __shfl_xor(mxp, o, 64));
    mxs = fmaxf(mxs, __shfl_xor(mxs, o, 64));
  }
  const float ep = __expf(p - mxp);
  const float es = __expf(s - mxs);
  float sp = ep, ss = es;
#pragma unroll
  for (int o = 32; o; o >>= 1) {
    sp += __shfl_xor(sp, o, 64);
    ss += __shfl_xor(ss, o, 64);
  }
  mP[(size_t)u * 64 + lane] = m * (ep / sp);
  mS[(size_t)u * 64 + lane] = m * (es / ss);
}

// ---- edge dot (edge-list, ILP-2) ----
__global__ void dot_k(const float* __restrict__ A, const float* __restrict__ Bm,
                      const int* __restrict__ src, const int* __restrict__ dst,
                      float* __restrict__ out, int E) {
  const int lane = threadIdx.x & 63;
  const int wid = (blockIdx.x * blockDim.x + threadIdx.x) >> 6;
  const int nw = (gridDim.x * blockDim.x) >> 6;
  for (int e0 = wid * 2; e0 < E; e0 += nw * 2) {
    const bool has1 = (e0 + 1 < E);
    const int s0 = src[e0], d0 = dst[e0];
    const int s1 = has1 ? src[e0 + 1] : s0;
    const int d1 = has1 ? dst[e0 + 1] : d0;
    float p0 = A[(size_t)s0 * 64 + lane] * Bm[(size_t)d0 * 64 + lane];
    float p1 = A[(size_t)s1 * 64 + lane] * Bm[(size_t)d1 * 64 + lane];
#pragma unroll
    for (int o = 32; o; o >>= 1) {
      p0 += __shfl_xor(p0, o, 64);
      p1 += __shfl_xor(p1, o, 64);
    }
    if (lane == 0) {
      out[e0] = p0;
      if (has1) out[e0 + 1] = p1;
    }
  }
}

// ---------------------------------------------------------------------------

static void build_csr(const int* key, const int* other, int E, int N,
                      int* rowptr, int* srt, int* cursor, int* bsum,
                      hipStream_t stream) {
  const int n1 = N + 1;
  hipMemsetAsync(cursor, 0, (size_t)n1 * 4, stream);
  hist_k<<<(E + 255) / 256, 256, 0, stream>>>(key, cursor, E);
  const int nb = (n1 + 1023) / 1024;
  scan1_k<<<nb, 256, 0, stream>>>(cursor, rowptr, bsum, n1);
  scan2_k<<<1, 64, 0, stream>>>(bsum, nb);
  scan3_k<<<(n1 + 255) / 256, 256, 0, stream>>>(rowptr, bsum, n1);
  hipMemcpyAsync(cursor, rowptr, (size_t)N * 4, hipMemcpyDeviceToDevice, stream);
  scatter_k<<<(E + 255) / 256, 256, 0, stream>>>(key, other, cursor, srt, E);
}

extern "C" void kernel_launch(void* const* d_in, const int* in_sizes, int n_in,
                              void* d_out, int out_size, void* d_ws, size_t ws_size,
                              hipStream_t stream) {
  const float* user_emb = (const float*)d_in[0];
  const float* item_emb = (const float*)d_in[1];
  const int* rate_src = (const int*)d_in[2];
  const int* rate_dst = (const int*)d_in[3];
  const int* link_src = (const int*)d_in[4];
  const int* link_dst = (const int*)d_in[5];
  const int* neg_rate_src = (const int*)d_in[6];
  const int* neg_rate_dst = (const int*)d_in[7];
  const int* neg_link_src = (const int*)d_in[8];
  const int* neg_link_dst = (const int*)d_in[9];
  const float* lam = (const float*)d_in[10];
  const float* gat_Wsrc = (const float*)d_in[11];
  const float* gat_bsrc = (const float*)d_in[12];
  const float* gat_Wdst = (const float*)d_in[13];
  const float* gat_bdst = (const float*)d_in[14];
  const float* gat_attn = (const float*)d_in[15];
  const float* W_out = (const float*)d_in[16];
  const float* b_out = (const float*)d_in[17];
  const float* cheb_W = (const float*)d_in[18];
  const float* cheb_b = (const float*)d_in[19];
  const float* Wc = (const float*)d_in[20];
  const float* bc = (const float*)d_in[21];
  const float* Wsm = (const float*)d_in[22];
  const float* bs = (const float*)d_in[23];
  const float* WpP = (const float*)d_in[24];
  const float* bpP = (const float*)d_in[25];
  const float* WpS = (const float*)d_in[26];
  const float* bpS = (const float*)d_in[27];

  const int NU = in_sizes[0] / 64;
  const int NI = in_sizes[1] / 64;
  const int NR = in_sizes[2];
  const int NL = in_sizes[4];
  const int NMAX = NU > NI ? NU : NI;
  const size_t MAT = (size_t)NMAX * 64;
  const int TILES_U = (NU + 63) >> 6;
  const int TILES_I = (NI + 63) >> 6;

  float* ws = (float*)d_ws;
  float* B0 = ws + 0 * MAT;
  float* B1 = ws + 1 * MAT;
  float* B2 = ws + 2 * MAT;
  float* B3 = ws + 3 * MAT;
  float* B4 = ws + 4 * MAT;
  float* B5 = ws + 5 * MAT;
  float* B6 = ws + 6 * MAT;
  float* B7 = ws + 7 * MAT;
  int* ip = (int*)(ws + 8 * MAT);
  int* rp_rd = ip;                   // NI+1
  int* rp_rs = rp_rd + (NI + 1);     // NU+1
  int* rp_ld = rp_rs + (NU + 1);     // NU+1
  int* srt_rd = rp_ld + (NU + 1);    // NR
  int* srt_rs = srt_rd + NR;         // NR
  int* srt_ld = srt_rs + NR;         // NL
  int* cursor = srt_ld + NL;         // NMAX+1
  int* bsum = cursor + (NMAX + 1);   // 256
  float* dinv = (float*)(bsum + 256);  // NU

  const int W64 = 64 * 64, B64 = 64;

  // ---- 3 CSR groupings ----
  build_csr(rate_dst, rate_src, NR, NI, rp_rd, srt_rd, cursor, bsum, stream);
  build_csr(rate_src, rate_dst, NR, NU, rp_rs, srt_rs, cursor, bsum, stream);
  build_csr(link_dst, link_src, NL, NU, rp_ld, srt_ld, cursor, bsum, stream);

  // ---- user projections (2x proj2): fs0->B0, fd1->B1 ; fd2->B2, fd3->B3 ----
  proj_k<2><<<TILES_U, 256, 0, stream>>>(
      user_emb, gat_Wsrc + 0 * W64, gat_Wdst + 1 * W64,
      gat_bsrc + 0 * B64, gat_bdst + 1 * B64, B0, B1, NU);
  proj_k<2><<<TILES_U, 256, 0, stream>>>(
      user_emb, gat_Wdst + 2 * W64, gat_Wdst + 3 * W64,
      gat_bdst + 2 * B64, gat_bdst + 3 * B64, B2, B3, NU);
  // ---- item projections (2-in-1): fd0->B4, fs1->B5 ----
  proj_k<2><<<TILES_I, 256, 0, stream>>>(
      item_emb, gat_Wdst + 0 * W64, gat_Wsrc + 1 * W64,
      gat_bdst + 0 * B64, gat_bsrc + 1 * B64, B4, B5, NI);

  // ---- gat0: (fs=B0, fd=B4) over rate-by-item -> B6 (h1_item) ----
  gat_csr_k<<<EDGE_BLOCKS, 256, 0, stream>>>(B0, B4, gat_attn + 0 * B64, rp_rd, srt_rd, B6, NI);
  // ---- gat1: (fs=B5, fd=B1) over rate-by-user -> B7 (h2_user) ----
  gat_csr_k<<<EDGE_BLOCKS, 256, 0, stream>>>(B5, B1, gat_attn + 1 * B64, rp_rs, srt_rs, B7, NU);

  // ---- fs2 = h1_item @ Ws2 -> B0 ; gat2 (fs=B0, fd=B2) -> B4 (item_infl) ----
  gemm_lds_k<1><<<TILES_I, 256, 0, stream>>>(B6, nullptr, nullptr,
                                             gat_Wsrc + 2 * W64, gat_bsrc + 2 * B64, B0, NI);
  gat_csr_k<<<EDGE_BLOCKS, 256, 0, stream>>>(B0, B2, gat_attn + 2 * B64, rp_rs, srt_rs, B4, NU);

  // ---- fs3 = h2_user @ Ws3 -> B5 ; gat3 (fs=B5, fd=B3) -> B2 (social_item) ----
  gemm_lds_k<1><<<TILES_U, 256, 0, stream>>>(B7, nullptr, nullptr,
                                             gat_Wsrc + 3 * W64, gat_bsrc + 3 * B64, B5, NU);
  gat_csr_k<<<EDGE_BLOCKS, 256, 0, stream>>>(B5, B3, gat_attn + 3 * B64, rp_ld, srt_ld, B2, NU);

  // ---- user_pref = [item_infl(B4), social_item(B2)] @ W_out + b_out -> B0 ----
  gemm_lds_k<2><<<TILES_U, 256, 0, stream>>>(B4, B2, nullptr, W_out, b_out, B0, NU);

  // ---- ChebConv(k=3): T1->B5, T2->B3, rst->B6 ----
  dinv_k<<<(NU + 255) / 256, 256, 0, stream>>>(rp_ld, dinv, NU);
  cheb_csr_k<1><<<EDGE_BLOCKS, 256, 0, stream>>>(user_emb, user_emb, nullptr, dinv, lam,
                                                 rp_ld, srt_ld, B5, NU);
  cheb_csr_k<2><<<EDGE_BLOCKS, 256, 0, stream>>>(B5, user_emb, B5, dinv, lam,
                                                 rp_ld, srt_ld, B3, NU);
  gemm_lds_k<3><<<TILES_U, 256, 0, stream>>>(user_emb, B5, B3, cheb_W, cheb_b, B6, NU);

  // ---- rst projections (2-in-1): fs4->B4, fd4->B2 ; gat4 -> B5 (user_social) ----
  proj_k<2><<<TILES_U, 256, 0, stream>>>(
      B6, gat_Wsrc + 4 * W64, gat_Wdst + 4 * W64,
      gat_bsrc + 4 * B64, gat_bdst + 4 * B64, B4, B2, NU);
  gat_csr_k<<<EDGE_BLOCKS, 256, 0, stream>>>(B4, B2, gat_attn + 4 * B64, rp_ld, srt_ld, B5, NU);

  // ---- mutualistic: h_uP->B4, h_uS->B2 (shared user_emb stage) ----
  dual128_k<true><<<TILES_U, 256, 0, stream>>>(
      B0, user_emb, B5, nullptr, Wc, Wsm, bc, bs, B4, B2, NU);
  mut_k<<<(NU + 3) / 4, 256, 0, stream>>>(B4, B2, B3, B7, NU);  // mP->B3, mS->B7
  // h_new_P->B0, h_new_S->B5
  dual128_k<false><<<TILES_U, 256, 0, stream>>>(
      B3, B4, B7, B2, WpP, WpS, bpP, bpS, B0, B5, NU);

  // ---- predictors ----
  float* out = (float*)d_out;
  dot_k<<<EDGE_BLOCKS, 256, 0, stream>>>(B0, item_emb, rate_src, rate_dst, out, NR);
  dot_k<<<EDGE_BLOCKS, 256, 0, stream>>>(B0, item_emb, neg_rate_src, neg_rate_dst, out + NR, NR);
  dot_k<<<EDGE_BLOCKS, 256, 0, stream>>>(B5, user_emb, link_src, link_dst, out + 2 * (size_t)NR, NL);
  dot_k<<<EDGE_BLOCKS, 256, 0, stream>>>(B5, user_emb, neg_link_src, neg_link_dst, out + 2 * (size_t)NR + NL, NL);
}